// Round 1
// baseline (405.993 us; speedup 1.0000x reference)
//
#include <hip/hip_runtime.h>
#include <hip/hip_bf16.h>

#define NN 8192
#define FIN 128
#define FOUT 64
#define ALPHA 0.2f
#define NCH 32             // j-chunks: 256 columns per block-iteration, 64 per wave

typedef __attribute__((ext_vector_type(8))) short short8;   // 8 bf16 (4 VGPRs)
typedef __attribute__((ext_vector_type(4))) float floatx4;

static __device__ __forceinline__ ushort f2bf(float f) {
    __hip_bfloat16 h = __float2bfloat16(f);
    return __builtin_bit_cast(ushort, h);
}

// K1: WhT[f][row] = bf16(x @ W); Wh1 = Wh@a[:64]; Wh2 = Wh@a[64:]  (fp32)
// grid NN/4 x 256: wave per row, lane = f  (unchanged, verified)
__global__ __launch_bounds__(256) void gat_proj(const float* __restrict__ x,
                                                const float* __restrict__ W,
                                                const float* __restrict__ a,
                                                ushort* __restrict__ WhT,
                                                float* __restrict__ Wh1,
                                                float* __restrict__ Wh2) {
    const int t = threadIdx.x;
    const int f = t & 63;
    const int rl = t >> 6;
    const int row = blockIdx.x * 4 + rl;
    const float4* __restrict__ x4 = (const float4*)(x + (size_t)row * FIN);

    float acc = 0.f;
    #pragma unroll
    for (int k4 = 0; k4 < FIN / 4; ++k4) {
        float4 xv = x4[k4];
        const int k = k4 * 4;
        acc = fmaf(xv.x, W[(k + 0) * FOUT + f], acc);
        acc = fmaf(xv.y, W[(k + 1) * FOUT + f], acc);
        acc = fmaf(xv.z, W[(k + 2) * FOUT + f], acc);
        acc = fmaf(xv.w, W[(k + 3) * FOUT + f], acc);
    }
    WhT[(size_t)f * NN + row] = f2bf(acc);

    float s1 = acc * a[f];
    float s2 = acc * a[FOUT + f];
    #pragma unroll
    for (int off = 32; off; off >>= 1) {
        s1 += __shfl_xor(s1, off, 64);
        s2 += __shfl_xor(s2, off, 64);
    }
    if (f == 0) { Wh1[row] = s1; Wh2[row] = s2; }
}

// K2 (restructured): waves split the j dimension; P lives entirely in registers
// in MFMA A-fragment layout. No per-chunk barriers, no P LDS roundtrip.
// Block = 256 thr (4 waves), owns 16 rows. Wave wv sweeps j = c*256 + wv*64 + [0,64).
// Lane (ln,quad): computes P[row=ln][k=quad*8+e] directly -> A-frag.
// adj register-prefetched one iteration ahead (double-buffered named sets).
// Epilogue: cross-wave acc/den reduce via LDS, normalize, ELU.
__global__ __launch_bounds__(256) void gat_attn(const int* __restrict__ adj,
                                                const ushort* __restrict__ WhT,
                                                const float* __restrict__ Wh1,
                                                const float* __restrict__ Wh2,
                                                float* __restrict__ out) {
    __shared__ __align__(16) float sWh2[NN];        // 32 KB, loaded once
    __shared__ float sAcc[4][4][16][16];            // [wv][ftile][m][n] 16 KB
    __shared__ float sDen[4][16];                   // [wv][row]

    const int t = threadIdx.x;
    const int lane = t & 63;
    const int wv = t >> 6;
    const int ln = lane & 15;
    const int quad = lane >> 4;
    const int row0 = blockIdx.x * 16;

    // stage Wh2 -> LDS cooperatively (8 float4 per thread)
    {
        const float4* __restrict__ s = (const float4*)Wh2;
        float4* d = (float4*)sWh2;
        #pragma unroll
        for (int i = 0; i < 8; ++i) d[i * 256 + t] = s[i * 256 + t];
    }

    const float wh1 = Wh1[row0 + ln];               // lane's row score-bias
    // adj row pointer: lane's 32B window at j = c*256 + wv*64 + quad*8 (+ks*32)
    const int4* __restrict__ ap =
        (const int4*)(adj + (size_t)(row0 + ln) * NN) + (wv * 16 + quad * 2);
    // WhT B-frag base: + ft*16*NN + c*256 + ks*32
    const ushort* __restrict__ bp = WhT + (size_t)ln * NN + wv * 64 + quad * 8;
    const float4* __restrict__ sW2v = (const float4*)sWh2;
    const int jq = wv * 16 + quad * 2;              // float4 index of lane's Wh2 slice

    floatx4 acc0 = {0.f, 0.f, 0.f, 0.f};
    floatx4 acc1 = {0.f, 0.f, 0.f, 0.f};
    floatx4 acc2 = {0.f, 0.f, 0.f, 0.f};
    floatx4 acc3 = {0.f, 0.f, 0.f, 0.f};
    float den = 0.f;

    __syncthreads();                                // sWh2 ready

#define LOADADJ(L0, H0, L1, H1, C) {                                         \
    L0 = ap[(C) * 64];                                                       \
    H0 = ap[(C) * 64 + 1];                                                   \
    L1 = ap[(C) * 64 + 8];                                                   \
    H1 = ap[(C) * 64 + 9];                                                   \
}

#define SCORE8(LO, HI, C, KS, AF) {                                          \
    float4 wa = sW2v[(C) * 64 + (KS) * 8 + jq];                              \
    float4 wb = sW2v[(C) * 64 + (KS) * 8 + jq + 1];                          \
    float s0 = wh1 + wa.x, s1 = wh1 + wa.y, s2 = wh1 + wa.z, s3 = wh1 + wa.w;\
    float s4 = wh1 + wb.x, s5 = wh1 + wb.y, s6 = wh1 + wb.z, s7 = wh1 + wb.w;\
    s0 = fmaxf(s0, ALPHA * s0); s1 = fmaxf(s1, ALPHA * s1);                  \
    s2 = fmaxf(s2, ALPHA * s2); s3 = fmaxf(s3, ALPHA * s3);                  \
    s4 = fmaxf(s4, ALPHA * s4); s5 = fmaxf(s5, ALPHA * s5);                  \
    s6 = fmaxf(s6, ALPHA * s6); s7 = fmaxf(s7, ALPHA * s7);                  \
    float p0 = (LO.x > 0) ? __expf(s0) : 0.f;                                \
    float p1 = (LO.y > 0) ? __expf(s1) : 0.f;                                \
    float p2 = (LO.z > 0) ? __expf(s2) : 0.f;                                \
    float p3 = (LO.w > 0) ? __expf(s3) : 0.f;                                \
    float p4 = (HI.x > 0) ? __expf(s4) : 0.f;                                \
    float p5 = (HI.y > 0) ? __expf(s5) : 0.f;                                \
    float p6 = (HI.z > 0) ? __expf(s6) : 0.f;                                \
    float p7 = (HI.w > 0) ? __expf(s7) : 0.f;                                \
    den += ((p0 + p1) + (p2 + p3)) + ((p4 + p5) + (p6 + p7));                \
    AF[0] = (short)f2bf(p0); AF[1] = (short)f2bf(p1);                        \
    AF[2] = (short)f2bf(p2); AF[3] = (short)f2bf(p3);                        \
    AF[4] = (short)f2bf(p4); AF[5] = (short)f2bf(p5);                        \
    AF[6] = (short)f2bf(p6); AF[7] = (short)f2bf(p7);                        \
}

#define BODY(L0, H0, L1, H1, C) {                                            \
    const ushort* bq = bp + (size_t)(C) * 256;                               \
    short8 b00 = *(const short8*)(bq);                                       \
    short8 b01 = *(const short8*)(bq + (size_t)16 * NN);                     \
    short8 b02 = *(const short8*)(bq + (size_t)32 * NN);                     \
    short8 b03 = *(const short8*)(bq + (size_t)48 * NN);                     \
    short8 b10 = *(const short8*)(bq + 32);                                  \
    short8 b11 = *(const short8*)(bq + (size_t)16 * NN + 32);                \
    short8 b12 = *(const short8*)(bq + (size_t)32 * NN + 32);                \
    short8 b13 = *(const short8*)(bq + (size_t)48 * NN + 32);                \
    short8 af0, af1;                                                         \
    SCORE8(L0, H0, C, 0, af0)                                                \
    SCORE8(L1, H1, C, 1, af1)                                                \
    acc0 = __builtin_amdgcn_mfma_f32_16x16x32_bf16(af0, b00, acc0, 0, 0, 0); \
    acc1 = __builtin_amdgcn_mfma_f32_16x16x32_bf16(af0, b01, acc1, 0, 0, 0); \
    acc2 = __builtin_amdgcn_mfma_f32_16x16x32_bf16(af0, b02, acc2, 0, 0, 0); \
    acc3 = __builtin_amdgcn_mfma_f32_16x16x32_bf16(af0, b03, acc3, 0, 0, 0); \
    acc0 = __builtin_amdgcn_mfma_f32_16x16x32_bf16(af1, b10, acc0, 0, 0, 0); \
    acc1 = __builtin_amdgcn_mfma_f32_16x16x32_bf16(af1, b11, acc1, 0, 0, 0); \
    acc2 = __builtin_amdgcn_mfma_f32_16x16x32_bf16(af1, b12, acc2, 0, 0, 0); \
    acc3 = __builtin_amdgcn_mfma_f32_16x16x32_bf16(af1, b13, acc3, 0, 0, 0); \
}

    // main loop: unroll-by-2 with named register sets (static indexing only),
    // adj prefetched one full iteration ahead of use.
    int4 xl0, xh0, xl1, xh1, yl0, yh0, yl1, yh1;
    LOADADJ(xl0, xh0, xl1, xh1, 0)
    for (int c = 0; c < NCH; c += 2) {
        LOADADJ(yl0, yh0, yl1, yh1, c + 1)
        BODY(xl0, xh0, xl1, xh1, c)
        const int c2 = (c + 2 < NCH) ? (c + 2) : 0;   // clamp: last prefetch unused
        LOADADJ(xl0, xh0, xl1, xh1, c2)
        BODY(yl0, yh0, yl1, yh1, c + 1)
    }

#undef BODY
#undef SCORE8
#undef LOADADJ

    // den: reduce over the 4 quad-copies of each row within the wave
    den += __shfl_xor(den, 16, 64);
    den += __shfl_xor(den, 32, 64);
    if (lane < 16) sDen[wv][lane] = den;

    // acc partials -> LDS  (D[m=quad*4+r][n=ln], verified C/D layout)
    #pragma unroll
    for (int r = 0; r < 4; ++r) {
        const int m = quad * 4 + r;
        sAcc[wv][0][m][ln] = acc0[r];
        sAcc[wv][1][m][ln] = acc1[r];
        sAcc[wv][2][m][ln] = acc2[r];
        sAcc[wv][3][m][ln] = acc3[r];
    }
    __syncthreads();

    // wave wv finalizes f-tile wv: sum 4 j-slice partials, normalize, ELU
    #pragma unroll
    for (int r = 0; r < 4; ++r) {
        const int m = quad * 4 + r;
        float d = sDen[0][m] + sDen[1][m] + sDen[2][m] + sDen[3][m];
        float o = (sAcc[0][wv][m][ln] + sAcc[1][wv][m][ln] +
                   sAcc[2][wv][m][ln] + sAcc[3][wv][m][ln]) / d;
        o = (o > 0.f) ? o : (__expf(o) - 1.f);
        out[(size_t)(row0 + m) * FOUT + wv * 16 + ln] = o;
    }
}

extern "C" void kernel_launch(void* const* d_in, const int* in_sizes, int n_in,
                              void* d_out, int out_size, void* d_ws, size_t ws_size,
                              hipStream_t stream) {
    const float* x   = (const float*)d_in[0];   // [N, FIN]
    const int*   adj = (const int*)  d_in[1];   // [N, N]
    const float* W   = (const float*)d_in[2];   // [FIN, FOUT]
    const float* a   = (const float*)d_in[3];   // [2*FOUT, 1]
    float* out = (float*)d_out;                 // [N, FOUT]

    // ws: WhT bf16 [64][8192] (1MB) | Wh1 f32 [8192] | Wh2 f32 [8192]
    ushort* WhT = (ushort*)d_ws;
    float* Wh1 = (float*)(WhT + (size_t)FOUT * NN);
    float* Wh2 = Wh1 + NN;

    gat_proj<<<NN / 4, 256, 0, stream>>>(x, W, a, WhT, Wh1, Wh2);
    gat_attn<<<NN / 16, 256, 0, stream>>>(adj, WhT, Wh1, Wh2, out);
}